// Round 1
// baseline (1805.576 us; speedup 1.0000x reference)
//
#include <hip/hip_runtime.h>
#include <math.h>

#define NN 100000
#define NE 1600000
#define FF 128
#define HH 64
#define CC 10
#define GG 128
#define BN_EPS 1e-5f

// ---------------- dual skinny GEMM: Yl = X@Wl, Yr = X@Wr, W is [K,64] ----------------
template<int K>
__global__ __launch_bounds__(256) void gemm_dual(const float* __restrict__ X,
                                                 const float* __restrict__ Wl,
                                                 const float* __restrict__ Wr,
                                                 float* __restrict__ Yl,
                                                 float* __restrict__ Yr) {
    __shared__ float sWl[K * 64];
    __shared__ float sWr[K * 64];
    const int tid = threadIdx.x;
    for (int i = tid; i < K * 64; i += 256) { sWl[i] = Wl[i]; sWr[i] = Wr[i]; }
    __syncthreads();
    const int row = blockIdx.x * 4 + (tid >> 6);
    const int col = tid & 63;
    if (row >= NN) return;
    const float* xrow = X + (size_t)row * K;
    float accl = 0.f, accr = 0.f;
#pragma unroll 8
    for (int k = 0; k < K; ++k) {
        const float xv = xrow[k];
        accl += xv * sWl[k * 64 + col];
        accr += xv * sWr[k * 64 + col];
    }
    Yl[(size_t)row * 64 + col] = accl;
    Yr[(size_t)row * 64 + col] = accr;
}

// ---------------- degree count ----------------
__global__ __launch_bounds__(256) void count_edges(const int* __restrict__ dst,
                                                   float* __restrict__ cnt) {
    const int e = blockIdx.x * 256 + threadIdx.x;
    if (e < NE) atomicAdd(&cnt[dst[e]], 1.0f);
}

// ---------------- edge scatter-add: one wave per edge, 64 channels ----------------
__global__ __launch_bounds__(256) void scatter_add(const int* __restrict__ src,
                                                   const int* __restrict__ dst,
                                                   const float* __restrict__ Y,
                                                   float* __restrict__ agg) {
    const int idx = blockIdx.x * 256 + threadIdx.x;   // over NE*64 = 102.4M
    const int e = idx >> 6;
    const int h = idx & 63;
    if (e < NE) {
        const int s = src[e];
        const int d = dst[e];
        atomicAdd(&agg[(size_t)d * 64 + h], Y[(size_t)s * 64 + h]);
    }
}

// ---------------- mean + bias + root + BN + ReLU epilogue ----------------
__global__ __launch_bounds__(256) void post_bn_relu(const float* __restrict__ agg,
                                                    const float* __restrict__ cnt,
                                                    const float* __restrict__ yr,
                                                    const float* __restrict__ bias,
                                                    const float* __restrict__ bng,
                                                    const float* __restrict__ bnb,
                                                    const float* __restrict__ bnm,
                                                    const float* __restrict__ bnv,
                                                    float* __restrict__ out) {
    const int idx = blockIdx.x * 256 + threadIdx.x;   // NN*64
    if (idx >= NN * 64) return;
    const int n = idx >> 6;
    const int c = idx & 63;
    const float mean = agg[idx] / fmaxf(cnt[n], 1.0f);
    const float h = mean + bias[c] + yr[idx];
    const float sc = bng[c] * rsqrtf(bnv[c] + BN_EPS);
    const float val = (h - bnm[c]) * sc + bnb[c];
    out[idx] = fmaxf(val, 0.0f);
}

// ---------------- global mean pool (sum + count) ----------------
__global__ __launch_bounds__(256) void pool_kernel(const float* __restrict__ h,
                                                   const int* __restrict__ batch,
                                                   float* __restrict__ gsum,
                                                   float* __restrict__ gcnt) {
    const int idx = blockIdx.x * 256 + threadIdx.x;   // NN*64
    if (idx >= NN * 64) return;
    const int n = idx >> 6;
    const int c = idx & 63;
    const int b = batch[n];
    atomicAdd(&gsum[b * 64 + c], h[idx]);
    if (c == 0) atomicAdd(&gcnt[b], 1.0f);
}

// ---------------- classifier head: one block (64 threads) per graph ----------------
__global__ __launch_bounds__(64) void head_kernel(const float* __restrict__ gsum,
                                                  const float* __restrict__ gcnt,
                                                  const float* __restrict__ Wc1,
                                                  const float* __restrict__ bc1,
                                                  const float* __restrict__ g3,
                                                  const float* __restrict__ b3,
                                                  const float* __restrict__ m3,
                                                  const float* __restrict__ v3,
                                                  const float* __restrict__ Wc2,
                                                  const float* __restrict__ bc2,
                                                  float* __restrict__ out) {
    __shared__ float sg[64];
    __shared__ float st[64];
    __shared__ float sl[10];
    __shared__ float sls;
    const int b = blockIdx.x;
    const int c = threadIdx.x;
    sg[c] = gsum[b * 64 + c] / fmaxf(gcnt[b], 1.0f);
    __syncthreads();
    float acc = bc1[c];
#pragma unroll
    for (int k = 0; k < 64; ++k) acc += sg[k] * Wc1[k * 64 + c];
    const float sc = g3[c] * rsqrtf(v3[c] + BN_EPS);
    st[c] = fmaxf((acc - m3[c]) * sc + b3[c], 0.0f);
    __syncthreads();
    if (c < CC) {
        float lg = bc2[c];
#pragma unroll
        for (int k = 0; k < 64; ++k) lg += st[k] * Wc2[k * CC + c];
        sl[c] = lg;
    }
    __syncthreads();
    if (c == 0) {
        float mx = sl[0];
        for (int i = 1; i < CC; ++i) mx = fmaxf(mx, sl[i]);
        float s = 0.f;
        for (int i = 0; i < CC; ++i) s += expf(sl[i] - mx);
        sls = mx + logf(s);
    }
    __syncthreads();
    if (c < CC) out[b * CC + c] = sl[c] - sls;
}

extern "C" void kernel_launch(void* const* d_in, const int* in_sizes, int n_in,
                              void* d_out, int out_size, void* d_ws, size_t ws_size,
                              hipStream_t stream) {
    // input order = setup_inputs() dict order
    const float* x    = (const float*)d_in[0];
    const int*   ei   = (const int*)d_in[1];      // [2, E]
    const int*   batch= (const int*)d_in[2];
    const float* W1l  = (const float*)d_in[3];
    const float* W1r  = (const float*)d_in[4];
    const float* b1   = (const float*)d_in[5];
    const float* W2l  = (const float*)d_in[6];
    const float* W2r  = (const float*)d_in[7];
    const float* b2   = (const float*)d_in[8];
    const float* bn1g = (const float*)d_in[9];
    const float* bn1b = (const float*)d_in[10];
    const float* bn1m = (const float*)d_in[11];
    const float* bn1v = (const float*)d_in[12];
    const float* bn2g = (const float*)d_in[13];
    const float* bn2b = (const float*)d_in[14];
    const float* bn2m = (const float*)d_in[15];
    const float* bn2v = (const float*)d_in[16];
    const float* bn3g = (const float*)d_in[17];
    const float* bn3b = (const float*)d_in[18];
    const float* bn3m = (const float*)d_in[19];
    const float* bn3v = (const float*)d_in[20];
    const float* Wc1  = (const float*)d_in[21];
    const float* bc1  = (const float*)d_in[22];
    const float* Wc2  = (const float*)d_in[23];
    const float* bc2  = (const float*)d_in[24];
    float* out = (float*)d_out;

    const int* src = ei;            // edge_index[0]
    const int* dst = ei + NE;       // edge_index[1]

    // workspace layout (floats)
    float* buf0 = (float*)d_ws;                       // N*64
    float* buf1 = buf0 + (size_t)NN * 64;             // N*64
    float* buf2 = buf1 + (size_t)NN * 64;             // N*64
    float* cnt  = buf2 + (size_t)NN * 64;             // N
    float* gsum = cnt + NN;                           // G*64
    float* gcnt = gsum + GG * 64;                     // G

    const size_t nodeBytes = (size_t)NN * 64 * sizeof(float);

    // ---- layer 1 ----
    hipMemsetAsync(buf2, 0, nodeBytes, stream);                 // agg1
    hipMemsetAsync(cnt, 0, (size_t)NN * sizeof(float), stream);
    gemm_dual<FF><<<NN / 4, 256, 0, stream>>>(x, W1l, W1r, buf0, buf1);   // y1l, y1r
    count_edges<<<(NE + 255) / 256, 256, 0, stream>>>(dst, cnt);
    scatter_add<<<(NE * 64) / 256, 256, 0, stream>>>(src, dst, buf0, buf2);
    post_bn_relu<<<(NN * 64) / 256, 256, 0, stream>>>(buf2, cnt, buf1, b1,
                                                      bn1g, bn1b, bn1m, bn1v, buf0); // h1

    // ---- layer 2 ----
    gemm_dual<HH><<<NN / 4, 256, 0, stream>>>(buf0, W2l, W2r, buf1, buf2); // y2l, y2r
    hipMemsetAsync(buf0, 0, nodeBytes, stream);                 // agg2
    scatter_add<<<(NE * 64) / 256, 256, 0, stream>>>(src, dst, buf1, buf0);
    post_bn_relu<<<(NN * 64) / 256, 256, 0, stream>>>(buf0, cnt, buf2, b2,
                                                      bn2g, bn2b, bn2m, bn2v, buf1); // h2

    // ---- pool + head ----
    hipMemsetAsync(gsum, 0, (size_t)(GG * 64 + GG) * sizeof(float), stream);
    pool_kernel<<<(NN * 64) / 256, 256, 0, stream>>>(buf1, batch, gsum, gcnt);
    head_kernel<<<GG, 64, 0, stream>>>(gsum, gcnt, Wc1, bc1,
                                       bn3g, bn3b, bn3m, bn3v, Wc2, bc2, out);
}

// Round 2
// 951.626 us; speedup vs baseline: 1.8974x; 1.8974x over previous
//
#include <hip/hip_runtime.h>
#include <math.h>

#define NN 100000
#define NE 1600000
#define FF 128
#define HH 64
#define CC 10
#define GG 128
#define BN_EPS 1e-5f
#define NB_SCAN 391   // ceil(NN/256)

// ---------------- dual skinny GEMM: Yl = X@Wl, Yr = X@Wr, W is [K,64] ----------------
template<int K>
__global__ __launch_bounds__(256) void gemm_dual(const float* __restrict__ X,
                                                 const float* __restrict__ Wl,
                                                 const float* __restrict__ Wr,
                                                 float* __restrict__ Yl,
                                                 float* __restrict__ Yr) {
    __shared__ float sWl[K * 64];
    __shared__ float sWr[K * 64];
    const int tid = threadIdx.x;
    for (int i = tid; i < K * 64; i += 256) { sWl[i] = Wl[i]; sWr[i] = Wr[i]; }
    __syncthreads();
    const int row = blockIdx.x * 4 + (tid >> 6);
    const int col = tid & 63;
    if (row >= NN) return;
    const float* xrow = X + (size_t)row * K;
    float accl = 0.f, accr = 0.f;
#pragma unroll 8
    for (int k = 0; k < K; ++k) {
        const float xv = xrow[k];
        accl += xv * sWl[k * 64 + col];
        accr += xv * sWr[k * 64 + col];
    }
    Yl[(size_t)row * 64 + col] = accl;
    Yr[(size_t)row * 64 + col] = accr;
}

// ---------------- CSR build: degree count ----------------
__global__ __launch_bounds__(256) void count_edges(const int* __restrict__ dst,
                                                   int* __restrict__ cnt) {
    const int e = blockIdx.x * 256 + threadIdx.x;
    if (e < NE) atomicAdd(&cnt[dst[e]], 1);
}

// ---------------- CSR build: 3-phase exclusive scan over cnt[NN] ----------------
__global__ __launch_bounds__(256) void scan_block(const int* __restrict__ cnt,
                                                  int* __restrict__ rp,
                                                  int* __restrict__ bsum) {
    __shared__ int s[256];
    const int tid = threadIdx.x;
    const int i = blockIdx.x * 256 + tid;
    const int v = (i < NN) ? cnt[i] : 0;
    s[tid] = v;
    __syncthreads();
    for (int off = 1; off < 256; off <<= 1) {
        int t = (tid >= off) ? s[tid - off] : 0;
        __syncthreads();
        s[tid] += t;
        __syncthreads();
    }
    if (i < NN) rp[i] = s[tid] - v;        // exclusive within block
    if (tid == 255) bsum[blockIdx.x] = s[255];
}

__global__ __launch_bounds__(512) void scan_bsums(int* __restrict__ bsum,
                                                  int* __restrict__ boff,
                                                  int* __restrict__ rp) {
    __shared__ int s[512];
    const int tid = threadIdx.x;
    const int v = (tid < NB_SCAN) ? bsum[tid] : 0;
    s[tid] = v;
    __syncthreads();
    for (int off = 1; off < 512; off <<= 1) {
        int t = (tid >= off) ? s[tid - off] : 0;
        __syncthreads();
        s[tid] += t;
        __syncthreads();
    }
    if (tid < NB_SCAN) boff[tid] = s[tid] - v;   // exclusive block offsets
    if (tid == 0) rp[NN] = NE;
}

__global__ __launch_bounds__(256) void scan_add(int* __restrict__ rp,
                                                const int* __restrict__ boff) {
    const int i = blockIdx.x * 256 + threadIdx.x;
    if (i < NN) rp[i] += boff[blockIdx.x];
}

// ---------------- CSR build: fill column (src) indices ----------------
__global__ __launch_bounds__(256) void csr_fill(const int* __restrict__ src,
                                                const int* __restrict__ dst,
                                                const int* __restrict__ rp,
                                                int* __restrict__ fill,
                                                int* __restrict__ col) {
    const int e = blockIdx.x * 256 + threadIdx.x;
    if (e < NE) {
        const int d = dst[e];
        const int pos = rp[d] + atomicAdd(&fill[d], 1);
        col[pos] = src[e];
    }
}

// ---------------- fused gather(mean) + bias + root + BN + ReLU ----------------
__global__ __launch_bounds__(256) void gather_post(const int* __restrict__ rp,
                                                   const int* __restrict__ col,
                                                   const float* __restrict__ Yl,
                                                   const float* __restrict__ Yr,
                                                   const float* __restrict__ bias,
                                                   const float* __restrict__ bng,
                                                   const float* __restrict__ bnb,
                                                   const float* __restrict__ bnm,
                                                   const float* __restrict__ bnv,
                                                   float* __restrict__ out) {
    const int node = blockIdx.x * 4 + (threadIdx.x >> 6);
    const int lane = threadIdx.x & 63;
    if (node >= NN) return;
    const int beg = rp[node];
    const int end = rp[node + 1];
    float acc = 0.f;
    for (int base = beg; base < end; base += 64) {
        const int m = end - base < 64 ? end - base : 64;
        const int sc = (lane < m) ? col[base + lane] : 0;   // coalesced col read
        for (int j = 0; j < m; ++j) {
            const int s = __shfl(sc, j);
            acc += Yl[(size_t)s * 64 + lane];               // coalesced 256B row read
        }
    }
    const float mean = acc / fmaxf((float)(end - beg), 1.0f);
    const float h = mean + bias[lane] + Yr[(size_t)node * 64 + lane];
    const float scale = bng[lane] * rsqrtf(bnv[lane] + BN_EPS);
    const float val = (h - bnm[lane]) * scale + bnb[lane];
    out[(size_t)node * 64 + lane] = fmaxf(val, 0.0f);
}

// ---------------- segmented global mean pool (batch is sorted) ----------------
__global__ __launch_bounds__(256) void pool_seg(const float* __restrict__ h,
                                                const int* __restrict__ batch,
                                                float* __restrict__ gsum,
                                                float* __restrict__ gcnt) {
    const int wave = blockIdx.x * 4 + (threadIdx.x >> 6);  // each wave: 256 nodes
    const int lane = threadIdx.x & 63;
    const int n0 = wave * 256;
    if (n0 >= NN) return;
    const int n1 = (n0 + 256 < NN) ? n0 + 256 : NN;
    int g = batch[n0];
    float acc = 0.f, c = 0.f;
    for (int n = n0; n < n1; ++n) {
        const int b = batch[n];
        if (b != g) {
            atomicAdd(&gsum[g * 64 + lane], acc);
            if (lane == 0) atomicAdd(&gcnt[g], c);
            acc = 0.f; c = 0.f; g = b;
        }
        acc += h[(size_t)n * 64 + lane];
        c += 1.0f;
    }
    atomicAdd(&gsum[g * 64 + lane], acc);
    if (lane == 0) atomicAdd(&gcnt[g], c);
}

// ---------------- classifier head: one block (64 threads) per graph ----------------
__global__ __launch_bounds__(64) void head_kernel(const float* __restrict__ gsum,
                                                  const float* __restrict__ gcnt,
                                                  const float* __restrict__ Wc1,
                                                  const float* __restrict__ bc1,
                                                  const float* __restrict__ g3,
                                                  const float* __restrict__ b3,
                                                  const float* __restrict__ m3,
                                                  const float* __restrict__ v3,
                                                  const float* __restrict__ Wc2,
                                                  const float* __restrict__ bc2,
                                                  float* __restrict__ out) {
    __shared__ float sg[64];
    __shared__ float st[64];
    __shared__ float sl[10];
    __shared__ float sls;
    const int b = blockIdx.x;
    const int c = threadIdx.x;
    sg[c] = gsum[b * 64 + c] / fmaxf(gcnt[b], 1.0f);
    __syncthreads();
    float acc = bc1[c];
#pragma unroll
    for (int k = 0; k < 64; ++k) acc += sg[k] * Wc1[k * 64 + c];
    const float sc = g3[c] * rsqrtf(v3[c] + BN_EPS);
    st[c] = fmaxf((acc - m3[c]) * sc + b3[c], 0.0f);
    __syncthreads();
    if (c < CC) {
        float lg = bc2[c];
#pragma unroll
        for (int k = 0; k < 64; ++k) lg += st[k] * Wc2[k * CC + c];
        sl[c] = lg;
    }
    __syncthreads();
    if (c == 0) {
        float mx = sl[0];
        for (int i = 1; i < CC; ++i) mx = fmaxf(mx, sl[i]);
        float s = 0.f;
        for (int i = 0; i < CC; ++i) s += expf(sl[i] - mx);
        sls = mx + logf(s);
    }
    __syncthreads();
    if (c < CC) out[b * CC + c] = sl[c] - sls;
}

extern "C" void kernel_launch(void* const* d_in, const int* in_sizes, int n_in,
                              void* d_out, int out_size, void* d_ws, size_t ws_size,
                              hipStream_t stream) {
    const float* x    = (const float*)d_in[0];
    const int*   ei   = (const int*)d_in[1];      // [2, E]
    const int*   batch= (const int*)d_in[2];
    const float* W1l  = (const float*)d_in[3];
    const float* W1r  = (const float*)d_in[4];
    const float* b1   = (const float*)d_in[5];
    const float* W2l  = (const float*)d_in[6];
    const float* W2r  = (const float*)d_in[7];
    const float* b2   = (const float*)d_in[8];
    const float* bn1g = (const float*)d_in[9];
    const float* bn1b = (const float*)d_in[10];
    const float* bn1m = (const float*)d_in[11];
    const float* bn1v = (const float*)d_in[12];
    const float* bn2g = (const float*)d_in[13];
    const float* bn2b = (const float*)d_in[14];
    const float* bn2m = (const float*)d_in[15];
    const float* bn2v = (const float*)d_in[16];
    const float* bn3g = (const float*)d_in[17];
    const float* bn3b = (const float*)d_in[18];
    const float* bn3m = (const float*)d_in[19];
    const float* bn3v = (const float*)d_in[20];
    const float* Wc1  = (const float*)d_in[21];
    const float* bc1  = (const float*)d_in[22];
    const float* Wc2  = (const float*)d_in[23];
    const float* bc2  = (const float*)d_in[24];
    float* out = (float*)d_out;

    const int* src = ei;            // edge_index[0]
    const int* dst = ei + NE;       // edge_index[1]

    // workspace layout
    float* buf0 = (float*)d_ws;                       // N*64 f32
    float* buf1 = buf0 + (size_t)NN * 64;             // N*64 f32
    float* buf2 = buf1 + (size_t)NN * 64;             // N*64 f32
    int*   icnt = (int*)(buf2 + (size_t)NN * 64);     // N int
    int*   rp   = icnt + NN;                          // N+1 int
    int*   ifll = rp + NN + 1;                        // N int
    int*   col  = ifll + NN;                          // E int
    int*   bsum = col + NE;                           // 512 int
    int*   boff = bsum + 512;                         // 512 int
    float* gsum = (float*)(boff + 512);               // G*64 f32
    float* gcnt = gsum + GG * 64;                     // G f32

    // ---- CSR build (once, reused by both layers) ----
    hipMemsetAsync(icnt, 0, (size_t)NN * sizeof(int), stream);
    hipMemsetAsync(ifll, 0, (size_t)NN * sizeof(int), stream);
    count_edges<<<(NE + 255) / 256, 256, 0, stream>>>(dst, icnt);
    scan_block<<<NB_SCAN, 256, 0, stream>>>(icnt, rp, bsum);
    scan_bsums<<<1, 512, 0, stream>>>(bsum, boff, rp);
    scan_add<<<NB_SCAN, 256, 0, stream>>>(rp, boff);
    csr_fill<<<(NE + 255) / 256, 256, 0, stream>>>(src, dst, rp, ifll, col);

    // ---- layer 1 ----
    gemm_dual<FF><<<NN / 4, 256, 0, stream>>>(x, W1l, W1r, buf0, buf1);   // y1l, y1r
    gather_post<<<NN / 4, 256, 0, stream>>>(rp, col, buf0, buf1, b1,
                                            bn1g, bn1b, bn1m, bn1v, buf2); // h1

    // ---- layer 2 ----
    gemm_dual<HH><<<NN / 4, 256, 0, stream>>>(buf2, W2l, W2r, buf0, buf1); // y2l, y2r
    gather_post<<<NN / 4, 256, 0, stream>>>(rp, col, buf0, buf1, b2,
                                            bn2g, bn2b, bn2m, bn2v, buf2); // h2

    // ---- pool + head ----
    hipMemsetAsync(gsum, 0, (size_t)(GG * 64 + GG) * sizeof(float), stream);
    pool_seg<<<98, 256, 0, stream>>>(buf2, batch, gsum, gcnt);
    head_kernel<<<GG, 64, 0, stream>>>(gsum, gcnt, Wc1, bc1,
                                       bn3g, bn3b, bn3m, bn3v, Wc2, bc2, out);
}

// Round 3
// 645.116 us; speedup vs baseline: 2.7988x; 1.4751x over previous
//
#include <hip/hip_runtime.h>
#include <hip/hip_bf16.h>
#include <math.h>

#define NN 100000
#define NE 1600000
#define FF 128
#define HH 64
#define CC 10
#define GG 128
#define BN_EPS 1e-5f
#define NB_SCAN 391   // ceil(NN/256)

typedef short v8bf __attribute__((ext_vector_type(8)));
typedef float v4f  __attribute__((ext_vector_type(4)));

__device__ inline ushort f2b(float x) {
    __hip_bfloat16 h = __float2bfloat16(x);
    return *reinterpret_cast<ushort*>(&h);
}

// ---------------- fp32 -> bf16 elementwise (vectorized) ----------------
__global__ __launch_bounds__(256) void f32_to_bf16_vec(const float* __restrict__ in,
                                                       ushort* __restrict__ out, int n4) {
    const int i = blockIdx.x * 256 + threadIdx.x;
    if (i >= n4) return;
    const float4 v = ((const float4*)in)[i];
    ushort4 o;
    o.x = f2b(v.x); o.y = f2b(v.y); o.z = f2b(v.z); o.w = f2b(v.w);
    ((ushort4*)out)[i] = o;
}

// ---------------- W [K][64] fp32 -> bf16 swizzled into MFMA B-fragment order ----------
// layout: frag index t = (ks*4 + ntile)*64 + lane ; 8 contiguous bf16 per t
// value j of frag t = W[ks*32 + (lane>>4)*8 + j][ntile*16 + (lane&15)]
template<int K>
__global__ __launch_bounds__(256) void w_swizzle(const float* __restrict__ Wl,
                                                 const float* __restrict__ Wr,
                                                 ushort* __restrict__ ol,
                                                 ushort* __restrict__ orr) {
    constexpr int T = (K / 32) * 4 * 64;
    const int t = blockIdx.x * 256 + threadIdx.x;
    if (t >= T) return;
    const int lane = t & 63, nt = (t >> 6) & 3, ks = t >> 8;
    const int m = lane & 15, quad = lane >> 4;
#pragma unroll
    for (int j = 0; j < 8; ++j) {
        const int kk = ks * 32 + quad * 8 + j;
        const int cc = nt * 16 + m;
        ol[t * 8 + j]  = f2b(Wl[kk * 64 + cc]);
        orr[t * 8 + j] = f2b(Wr[kk * 64 + cc]);
    }
}

// ---------------- dual MFMA GEMM: Yl = X@Wl, Yr = X@Wr ----------------
// X bf16 [N][K] row-major; W pre-swizzled; Y fp32 [N][64].
// wave = 16 rows x 32 cols x both mats; block 256 = 4 waves = one 32-row tile,
// with cols split between wave pairs. Grid-stride over TPB tiles per block.
template<int K, int TPB>
__global__ __launch_bounds__(256) void gemm_mfma(const ushort* __restrict__ X,
                                                 const ushort* __restrict__ Bl,
                                                 const ushort* __restrict__ Br,
                                                 float* __restrict__ Yl,
                                                 float* __restrict__ Yr) {
    constexpr int KS = K / 32;
    const int lane  = threadIdx.x & 63;
    const int wave  = threadIdx.x >> 6;
    const int nhalf = wave & 1;        // cols 0..31 or 32..63
    const int rsub  = wave >> 1;       // 16-row half of the 32-row tile
    const int m = lane & 15, quad = lane >> 4;

    // B fragments held in registers across all tiles
    v8bf bl[KS][2], br[KS][2];
#pragma unroll
    for (int ks = 0; ks < KS; ++ks)
#pragma unroll
        for (int nt = 0; nt < 2; ++nt) {
            const int nti = nhalf * 2 + nt;
            bl[ks][nt] = *(const v8bf*)(Bl + ((size_t)(ks * 4 + nti) * 64 + lane) * 8);
            br[ks][nt] = *(const v8bf*)(Br + ((size_t)(ks * 4 + nti) * 64 + lane) * 8);
        }

    for (int it = 0; it < TPB; ++it) {
        const int bt = blockIdx.x * TPB + it;
        const int row0 = bt * 32 + rsub * 16;
        if (row0 >= NN) return;
        const v4f z = {0.f, 0.f, 0.f, 0.f};
        v4f accl[2] = {z, z}, accr[2] = {z, z};
        const ushort* xrow = X + (size_t)(row0 + m) * K + quad * 8;
#pragma unroll
        for (int ks = 0; ks < KS; ++ks) {
            const v8bf a = *(const v8bf*)(xrow + ks * 32);
#pragma unroll
            for (int nt = 0; nt < 2; ++nt) {
                accl[nt] = __builtin_amdgcn_mfma_f32_16x16x32_bf16(a, bl[ks][nt], accl[nt], 0, 0, 0);
                accr[nt] = __builtin_amdgcn_mfma_f32_16x16x32_bf16(a, br[ks][nt], accr[nt], 0, 0, 0);
            }
        }
#pragma unroll
        for (int nt = 0; nt < 2; ++nt) {
            const int cc = nhalf * 32 + nt * 16 + m;
#pragma unroll
            for (int r = 0; r < 4; ++r) {
                const size_t off = (size_t)(row0 + quad * 4 + r) * 64 + cc;
                Yl[off] = accl[nt][r];
                Yr[off] = accr[nt][r];
            }
        }
    }
}

// ---------------- CSR build: degree count ----------------
__global__ __launch_bounds__(256) void count_edges(const int* __restrict__ dst,
                                                   int* __restrict__ cnt) {
    const int e = blockIdx.x * 256 + threadIdx.x;
    if (e < NE) atomicAdd(&cnt[dst[e]], 1);
}

// ---------------- CSR build: 3-phase exclusive scan ----------------
__global__ __launch_bounds__(256) void scan_block(const int* __restrict__ cnt,
                                                  int* __restrict__ rp,
                                                  int* __restrict__ bsum) {
    __shared__ int s[256];
    const int tid = threadIdx.x;
    const int i = blockIdx.x * 256 + tid;
    const int v = (i < NN) ? cnt[i] : 0;
    s[tid] = v;
    __syncthreads();
    for (int off = 1; off < 256; off <<= 1) {
        int t = (tid >= off) ? s[tid - off] : 0;
        __syncthreads();
        s[tid] += t;
        __syncthreads();
    }
    if (i < NN) rp[i] = s[tid] - v;
    if (tid == 255) bsum[blockIdx.x] = s[255];
}

__global__ __launch_bounds__(512) void scan_bsums(int* __restrict__ bsum,
                                                  int* __restrict__ boff,
                                                  int* __restrict__ rp) {
    __shared__ int s[512];
    const int tid = threadIdx.x;
    const int v = (tid < NB_SCAN) ? bsum[tid] : 0;
    s[tid] = v;
    __syncthreads();
    for (int off = 1; off < 512; off <<= 1) {
        int t = (tid >= off) ? s[tid - off] : 0;
        __syncthreads();
        s[tid] += t;
        __syncthreads();
    }
    if (tid < NB_SCAN) boff[tid] = s[tid] - v;
    if (tid == 0) rp[NN] = NE;
}

__global__ __launch_bounds__(256) void scan_add(int* __restrict__ rp,
                                                const int* __restrict__ boff) {
    const int i = blockIdx.x * 256 + threadIdx.x;
    if (i < NN) rp[i] += boff[blockIdx.x];
}

__global__ __launch_bounds__(256) void csr_fill(const int* __restrict__ src,
                                                const int* __restrict__ dst,
                                                const int* __restrict__ rp,
                                                int* __restrict__ fill,
                                                int* __restrict__ col) {
    const int e = blockIdx.x * 256 + threadIdx.x;
    if (e < NE) {
        const int d = dst[e];
        const int pos = rp[d] + atomicAdd(&fill[d], 1);
        col[pos] = src[e];
    }
}

// ---------------- fused gather(mean) + bias + root + BN + ReLU ----------------
template<bool BF16OUT>
__global__ __launch_bounds__(256) void gather_post(const int* __restrict__ rp,
                                                   const int* __restrict__ col,
                                                   const float* __restrict__ Yl,
                                                   const float* __restrict__ Yr,
                                                   const float* __restrict__ bias,
                                                   const float* __restrict__ bng,
                                                   const float* __restrict__ bnb,
                                                   const float* __restrict__ bnm,
                                                   const float* __restrict__ bnv,
                                                   void* __restrict__ outp) {
    const int node = blockIdx.x * 4 + (threadIdx.x >> 6);
    const int lane = threadIdx.x & 63;
    if (node >= NN) return;
    const int beg = rp[node];
    const int end = rp[node + 1];
    float acc = 0.f;
    for (int base = beg; base < end; base += 64) {
        const int mm = end - base < 64 ? end - base : 64;
        const int sc = (lane < mm) ? col[base + lane] : 0;
        for (int j = 0; j < mm; ++j) {
            const int s = __shfl(sc, j);
            acc += Yl[(size_t)s * 64 + lane];
        }
    }
    const float mean = acc / fmaxf((float)(end - beg), 1.0f);
    const float h = mean + bias[lane] + Yr[(size_t)node * 64 + lane];
    const float scale = bng[lane] * rsqrtf(bnv[lane] + BN_EPS);
    const float val = fmaxf((h - bnm[lane]) * scale + bnb[lane], 0.0f);
    const size_t idx = (size_t)node * 64 + lane;
    if (BF16OUT) ((ushort*)outp)[idx] = f2b(val);
    else         ((float*)outp)[idx] = val;
}

// ---------------- segmented global mean pool (batch is sorted) ----------------
__global__ __launch_bounds__(256) void pool_seg(const float* __restrict__ h,
                                                const int* __restrict__ batch,
                                                float* __restrict__ gsum,
                                                float* __restrict__ gcnt) {
    const int wave = blockIdx.x * 4 + (threadIdx.x >> 6);
    const int lane = threadIdx.x & 63;
    const int n0 = wave * 256;
    if (n0 >= NN) return;
    const int n1 = (n0 + 256 < NN) ? n0 + 256 : NN;
    int g = batch[n0];
    float acc = 0.f, c = 0.f;
    for (int n = n0; n < n1; ++n) {
        const int b = batch[n];
        if (b != g) {
            atomicAdd(&gsum[g * 64 + lane], acc);
            if (lane == 0) atomicAdd(&gcnt[g], c);
            acc = 0.f; c = 0.f; g = b;
        }
        acc += h[(size_t)n * 64 + lane];
        c += 1.0f;
    }
    atomicAdd(&gsum[g * 64 + lane], acc);
    if (lane == 0) atomicAdd(&gcnt[g], c);
}

// ---------------- classifier head ----------------
__global__ __launch_bounds__(64) void head_kernel(const float* __restrict__ gsum,
                                                  const float* __restrict__ gcnt,
                                                  const float* __restrict__ Wc1,
                                                  const float* __restrict__ bc1,
                                                  const float* __restrict__ g3,
                                                  const float* __restrict__ b3,
                                                  const float* __restrict__ m3,
                                                  const float* __restrict__ v3,
                                                  const float* __restrict__ Wc2,
                                                  const float* __restrict__ bc2,
                                                  float* __restrict__ out) {
    __shared__ float sg[64];
    __shared__ float st[64];
    __shared__ float sl[10];
    __shared__ float sls;
    const int b = blockIdx.x;
    const int c = threadIdx.x;
    sg[c] = gsum[b * 64 + c] / fmaxf(gcnt[b], 1.0f);
    __syncthreads();
    float acc = bc1[c];
#pragma unroll
    for (int k = 0; k < 64; ++k) acc += sg[k] * Wc1[k * 64 + c];
    const float sc = g3[c] * rsqrtf(v3[c] + BN_EPS);
    st[c] = fmaxf((acc - m3[c]) * sc + b3[c], 0.0f);
    __syncthreads();
    if (c < CC) {
        float lg = bc2[c];
#pragma unroll
        for (int k = 0; k < 64; ++k) lg += st[k] * Wc2[k * CC + c];
        sl[c] = lg;
    }
    __syncthreads();
    if (c == 0) {
        float mx = sl[0];
        for (int i = 1; i < CC; ++i) mx = fmaxf(mx, sl[i]);
        float s = 0.f;
        for (int i = 0; i < CC; ++i) s += expf(sl[i] - mx);
        sls = mx + logf(s);
    }
    __syncthreads();
    if (c < CC) out[b * CC + c] = sl[c] - sls;
}

extern "C" void kernel_launch(void* const* d_in, const int* in_sizes, int n_in,
                              void* d_out, int out_size, void* d_ws, size_t ws_size,
                              hipStream_t stream) {
    const float* x    = (const float*)d_in[0];
    const int*   ei   = (const int*)d_in[1];
    const int*   batch= (const int*)d_in[2];
    const float* W1l  = (const float*)d_in[3];
    const float* W1r  = (const float*)d_in[4];
    const float* b1   = (const float*)d_in[5];
    const float* W2l  = (const float*)d_in[6];
    const float* W2r  = (const float*)d_in[7];
    const float* b2   = (const float*)d_in[8];
    const float* bn1g = (const float*)d_in[9];
    const float* bn1b = (const float*)d_in[10];
    const float* bn1m = (const float*)d_in[11];
    const float* bn1v = (const float*)d_in[12];
    const float* bn2g = (const float*)d_in[13];
    const float* bn2b = (const float*)d_in[14];
    const float* bn2m = (const float*)d_in[15];
    const float* bn2v = (const float*)d_in[16];
    const float* bn3g = (const float*)d_in[17];
    const float* bn3b = (const float*)d_in[18];
    const float* bn3m = (const float*)d_in[19];
    const float* bn3v = (const float*)d_in[20];
    const float* Wc1  = (const float*)d_in[21];
    const float* bc1  = (const float*)d_in[22];
    const float* Wc2  = (const float*)d_in[23];
    const float* bc2  = (const float*)d_in[24];
    float* out = (float*)d_out;

    const int* src = ei;
    const int* dst = ei + NE;

    // workspace layout (bytes-aligned to 16)
    // region A (25.6 MB): xb (bf16 [N][128]) -> later h1b (bf16 [N][64]) -> later h2 (f32 [N][64])
    char* p = (char*)d_ws;
    ushort* xb   = (ushort*)p;                 p += (size_t)NN * FF * 2;   // 25.6 MB
    float*  yl   = (float*)p;                  p += (size_t)NN * 64 * 4;   // 25.6 MB
    float*  yr   = (float*)p;                  p += (size_t)NN * 64 * 4;   // 25.6 MB
    ushort* w1ls = (ushort*)p;                 p += (size_t)FF * 64 * 2;
    ushort* w1rs = (ushort*)p;                 p += (size_t)FF * 64 * 2;
    ushort* w2ls = (ushort*)p;                 p += (size_t)HH * 64 * 2;
    ushort* w2rs = (ushort*)p;                 p += (size_t)HH * 64 * 2;
    int*   icnt  = (int*)p;                    p += (size_t)NN * 4;
    int*   rp    = (int*)p;                    p += (size_t)(NN + 1) * 4;
    int*   ifll  = (int*)p;                    p += (size_t)NN * 4;
    int*   col   = (int*)p;                    p += (size_t)NE * 4;        // 6.4 MB
    int*   bsum  = (int*)p;                    p += 512 * 4;
    int*   boff  = (int*)p;                    p += 512 * 4;
    float* gsum  = (float*)p;                  p += (size_t)GG * 64 * 4;
    float* gcnt  = (float*)p;                  p += (size_t)GG * 4;

    ushort* h1b = xb;            // aliases region A: xb dead after gemm1
    float*  h2  = (float*)xb;    // aliases region A: h1b dead after gemm2

    // ---- CSR build ----
    hipMemsetAsync(icnt, 0, (size_t)NN * sizeof(int), stream);
    hipMemsetAsync(ifll, 0, (size_t)NN * sizeof(int), stream);
    count_edges<<<(NE + 255) / 256, 256, 0, stream>>>(dst, icnt);
    scan_block<<<NB_SCAN, 256, 0, stream>>>(icnt, rp, bsum);
    scan_bsums<<<1, 512, 0, stream>>>(bsum, boff, rp);
    scan_add<<<NB_SCAN, 256, 0, stream>>>(rp, boff);
    csr_fill<<<(NE + 255) / 256, 256, 0, stream>>>(src, dst, rp, ifll, col);

    // ---- bf16 conversions / swizzles ----
    f32_to_bf16_vec<<<(NN * FF / 4 + 255) / 256, 256, 0, stream>>>(x, xb, NN * FF / 4);
    w_swizzle<FF><<<((FF / 32) * 256 + 255) / 256, 256, 0, stream>>>(W1l, W1r, w1ls, w1rs);
    w_swizzle<HH><<<((HH / 32) * 256 + 255) / 256, 256, 0, stream>>>(W2l, W2r, w2ls, w2rs);

    // ---- layer 1 ----
    gemm_mfma<FF, 5><<<625, 256, 0, stream>>>(xb, w1ls, w1rs, yl, yr);
    gather_post<true><<<NN / 4, 256, 0, stream>>>(rp, col, yl, yr, b1,
                                                  bn1g, bn1b, bn1m, bn1v, (void*)h1b);

    // ---- layer 2 ----
    gemm_mfma<HH, 5><<<625, 256, 0, stream>>>(h1b, w2ls, w2rs, yl, yr);
    gather_post<false><<<NN / 4, 256, 0, stream>>>(rp, col, yl, yr, b2,
                                                   bn2g, bn2b, bn2m, bn2v, (void*)h2);

    // ---- pool + head ----
    hipMemsetAsync(gsum, 0, (size_t)(GG * 64 + GG) * sizeof(float), stream);
    pool_seg<<<98, 256, 0, stream>>>(h2, batch, gsum, gcnt);
    head_kernel<<<GG, 64, 0, stream>>>(gsum, gcnt, Wc1, bc1,
                                       bn3g, bn3b, bn3m, bn3v, Wc2, bc2, out);
}